// Round 1
// 653.370 us; speedup vs baseline: 1.1600x; 1.1600x over previous
//
#include <hip/hip_runtime.h>

#define B_ 8
#define T_ 1024
#define C_ 1024
#define E_ 8
#define H_ 4096

typedef float v4f __attribute__((ext_vector_type(4)));
typedef short v8s __attribute__((ext_vector_type(8)));

__device__ __forceinline__ unsigned short f2bf(float f) {
  union { float f; unsigned int u; } x; x.f = f;
  unsigned int r = x.u + 0x7fffu + ((x.u >> 16) & 1u);
  return (unsigned short)(r >> 16);
}

__device__ __forceinline__ void async_load16(const unsigned short* g, unsigned short* l) {
  __builtin_amdgcn_global_load_lds(
      (const __attribute__((address_space(1))) void*)g,
      (__attribute__((address_space(3))) void*)l, 16, 0, 0);
}

// ---------------- router phase (unchanged) ----------------

__global__ void k_meanpart(const float* __restrict__ x, float* __restrict__ part,
                           unsigned short* __restrict__ xb) {
  int b = blockIdx.x >> 5, tc = blockIdx.x & 31;
  int c4 = threadIdx.x * 4;
  const size_t base = (size_t)b * T_ * C_ + (size_t)tc * 32 * C_ + c4;
  const float* xp = x + base;
  v4f s = {0.f, 0.f, 0.f, 0.f};
  for (int t = 0; t < 32; ++t) {
    v4f v = *(const v4f*)(xp + (size_t)t * C_);
    s += v;
    ushort4 o;
    o.x = f2bf(v.x); o.y = f2bf(v.y); o.z = f2bf(v.z); o.w = f2bf(v.w);
    *(ushort4*)(xb + base + (size_t)t * C_) = o;
  }
  *(v4f*)(part + (size_t)(tc * B_ + b) * C_ + c4) = s;
}

__global__ void k_router(const float* __restrict__ part, const float* __restrict__ rw,
                         int* __restrict__ sel, float* __restrict__ wv,
                         float* __restrict__ loss_out) {
  __shared__ float seq[B_ * C_];
  __shared__ float red[B_ * E_][4];
  __shared__ float pr[B_][E_];
  __shared__ int ss[B_][2];
  const int tid = threadIdx.x;
  for (int idx = tid; idx < B_ * C_; idx += 256) {
    float s = 0.f;
#pragma unroll
    for (int tc = 0; tc < 32; ++tc) s += part[(size_t)tc * B_ * C_ + idx];
    seq[idx] = s * (1.0f / T_);
  }
  __syncthreads();
  {
    int pair = tid >> 2, sub = tid & 3;
    int b = pair >> 3, e = pair & 7;
    float acc = 0.f;
    const float* sp = seq + b * C_ + sub * 256;
    const float* wp = rw + e * C_ + sub * 256;
    for (int c = 0; c < 256; ++c) acc += sp[c] * wp[c];
    red[pair][sub] = acc;
  }
  __syncthreads();
  if (tid < B_ * E_)
    pr[tid >> 3][tid & 7] = red[tid][0] + red[tid][1] + red[tid][2] + red[tid][3];
  __syncthreads();
  if (tid < B_) {
    int b = tid;
    float mx = pr[b][0];
#pragma unroll
    for (int e = 1; e < E_; ++e) mx = fmaxf(mx, pr[b][e]);
    float p[E_]; float sum = 0.f;
#pragma unroll
    for (int e = 0; e < E_; ++e) { p[e] = __expf(pr[b][e] - mx); sum += p[e]; }
    float inv = 1.0f / sum;
#pragma unroll
    for (int e = 0; e < E_; ++e) { p[e] *= inv; pr[b][e] = p[e]; }
    int i0 = 0;
#pragma unroll
    for (int e = 1; e < E_; ++e) if (p[e] > p[i0]) i0 = e;
    int i1 = (i0 == 0) ? 1 : 0;
#pragma unroll
    for (int e = 0; e < E_; ++e) if (e != i0 && p[e] > p[i1]) i1 = e;
    float s2 = p[i0] + p[i1];
    sel[b * 2 + 0] = i0; sel[b * 2 + 1] = i1;
    wv[b * 2 + 0] = p[i0] / s2; wv[b * 2 + 1] = p[i1] / s2;
    ss[b][0] = i0; ss[b][1] = i1;
  }
  __syncthreads();
  if (tid == 0) {
    float loss = 0.f;
    for (int e = 0; e < E_; ++e) {
      float imp = 0.f, ld = 0.f;
      for (int b = 0; b < B_; ++b) {
        imp += pr[b][e];
        ld += ((ss[b][0] == e) || (ss[b][1] == e)) ? 1.f : 0.f;
      }
      loss += (imp / (float)B_) * (ld / (float)B_);
    }
    loss_out[0] = loss * (float)E_;
  }
}

// ---------------- transpose+cast (unchanged) ----------------
__global__ void k_transpose(const float* __restrict__ src, unsigned short* __restrict__ dst,
                            int R, int Cc) {
  __shared__ float tile[64][65];
  const size_t sl = (size_t)blockIdx.z * R * Cc;
  int c0 = blockIdx.x * 64, r0 = blockIdx.y * 64;
  int tx = threadIdx.x & 15, ty = threadIdx.x >> 4;
#pragma unroll
  for (int p = 0; p < 4; ++p) {
    int r = p * 16 + ty;
    v4f v = *(const v4f*)(src + sl + (size_t)(r0 + r) * Cc + c0 + tx * 4);
    tile[r][tx * 4 + 0] = v.x; tile[r][tx * 4 + 1] = v.y;
    tile[r][tx * 4 + 2] = v.z; tile[r][tx * 4 + 3] = v.w;
  }
  __syncthreads();
#pragma unroll
  for (int p = 0; p < 4; ++p) {
    int c = p * 16 + ty;
    int rr = tx * 4;
    ushort4 o;
    o.x = f2bf(tile[rr + 0][c]); o.y = f2bf(tile[rr + 1][c]);
    o.z = f2bf(tile[rr + 2][c]); o.w = f2bf(tile[rr + 3][c]);
    *(ushort4*)(dst + sl + (size_t)(c0 + c) * R + r0 + rr) = o;
  }
}

// ---------------- 256x256 8-phase GEMM core (BK=64, 8 waves, 128 KiB LDS) ----------------
// LDS (shorts): buf d at d*32768; regions within buf: A-lo 0, A-hi 8192, B-lo 16384, B-hi 24576.
// Each region: 128 rows x 64 cols bf16, row stride 64 shorts; chunk (8 bf16) c of row r stored at
// physical chunk c ^ (r&7)  (XOR swizzle; staged via pre-swizzled GLOBAL source, linear LDS dest).
// Tile t (BK=64) -> buf t&1. Iteration computes tiles {t0=2I, t1=2I+1}, stages:
//   ph1:A-lo(t1) ph2:A-hi(t1) ph3:B-lo(t0+2) ph4:B-hi(t0+2) ph5:A-lo(t0+2) ph6:A-hi(t0+2)
//   ph7:B-lo(t1+2) ph8:B-hi(t1+2);  vmcnt(4) at ph4/ph8 (2 half-tiles in flight).
// Reads per tile window (3 phases): {A i0-3 + B j0-1}, {B j2-3}, {A i4-7}, {} -> region retire
// before its re-stage phase (B after +2, A after +3). Verified against both hazards on paper.

#define BARv() __builtin_amdgcn_s_barrier()
#define LGK0() asm volatile("s_waitcnt lgkmcnt(0)" ::: "memory")
#define VMC4() asm volatile("s_waitcnt vmcnt(4)" ::: "memory")
#define VMC0() asm volatile("s_waitcnt vmcnt(0)" ::: "memory")

__device__ __forceinline__ void gemm256(const unsigned short* __restrict__ Ag,
                                        const unsigned short* __restrict__ Bg,
                                        int lda, int ldb, int Kd,
                                        unsigned short* LDS, v4f (&acc)[8][4]) {
  const int tid = threadIdx.x;
  const int lane = tid & 63;
  const int w = __builtin_amdgcn_readfirstlane(tid >> 6);
  const int wm = w >> 2, wn = w & 3;
  const int rr = lane & 15, q = lane >> 4, s7 = rr & 7;
  const int ck0 = (q ^ s7) * 8;          // chunk for kk=0, swizzled
  const int ck1 = ((4 | q) ^ s7) * 8;    // chunk for kk=1, swizzled
  const int aoff = wm * 8192 + rr * 64;
  const int boff = 16384 + (wn >> 1) * 8192 + (wn & 1) * 4096 + rr * 64;
  const int w8 = w * 8;
  const int l3 = lane >> 3;
  const int srow = w8 + l3;                    // staged row within 64-row half
  const int sel8 = ((lane & 7) ^ l3) * 8;      // pre-swizzled global chunk
  v8s af[4][2], bfr[4][2];

#define STG(gb, ld, reg) do { \
    const unsigned short* _g = (gb) + (size_t)srow * (ld) + sel8; \
    async_load16(_g, LDS + (reg) + w8 * 64); \
    async_load16(_g + (size_t)64 * (ld), LDS + (reg) + 4096 + w8 * 64); \
  } while (0)

#define RDA(i2, qi, bs) do { \
    af[i2][0] = *(const v8s*)&LDS[(bs) + aoff + ((qi)*4+(i2))*1024 + ck0]; \
    af[i2][1] = *(const v8s*)&LDS[(bs) + aoff + ((qi)*4+(i2))*1024 + ck1]; \
  } while (0)

#define RDB(j, bs) do { \
    bfr[j][0] = *(const v8s*)&LDS[(bs) + boff + (j)*1024 + ck0]; \
    bfr[j][1] = *(const v8s*)&LDS[(bs) + boff + (j)*1024 + ck1]; \
  } while (0)

#define QUAD(qi, qj) do { \
    __builtin_amdgcn_s_setprio(1); \
    _Pragma("unroll") for (int _i = 0; _i < 4; ++_i) \
    _Pragma("unroll") for (int _j = 0; _j < 2; ++_j) { \
      acc[(qi)*4+_i][(qj)*2+_j] = __builtin_amdgcn_mfma_f32_16x16x32_bf16( \
          af[_i][0], bfr[(qj)*2+_j][0], acc[(qi)*4+_i][(qj)*2+_j], 0, 0, 0); \
      acc[(qi)*4+_i][(qj)*2+_j] = __builtin_amdgcn_mfma_f32_16x16x32_bf16( \
          af[_i][1], bfr[(qj)*2+_j][1], acc[(qi)*4+_i][(qj)*2+_j], 0, 0, 0); \
    } \
    __builtin_amdgcn_s_setprio(0); \
  } while (0)

  // prologue: tile0 fully (buf0) + tile1 B halves (buf1)  [12 loads/thread]
  STG(Ag, lda, 0);
  STG(Ag + (size_t)128 * lda, lda, 8192);
  STG(Bg, ldb, 16384);
  STG(Bg + (size_t)128 * ldb, ldb, 24576);
  STG(Bg + 64, ldb, 32768 + 16384);
  STG(Bg + (size_t)128 * ldb + 64, ldb, 32768 + 24576);
  VMC4();   // tile0 landed (only tile1-B may remain in flight)
  BARv();

  const int NI = Kd >> 7;
  for (int I = 0; I < NI; ++I) {
    const int k0 = I << 7;
    const bool last = (I == NI - 1);
    // ---- tile t0 (buf0) ----
    // ph1
    RDA(0,0,0); RDA(1,0,0); RDA(2,0,0); RDA(3,0,0); RDB(0,0); RDB(1,0);
    STG(Ag + k0 + 64, lda, 32768 + 0);
    BARv(); LGK0(); QUAD(0,0); BARv();
    // ph2
    RDB(2,0); RDB(3,0);
    STG(Ag + (size_t)128 * lda + k0 + 64, lda, 32768 + 8192);
    BARv(); LGK0(); QUAD(0,1); BARv();
    // ph3
    RDA(0,1,0); RDA(1,1,0); RDA(2,1,0); RDA(3,1,0);
    if (!last) STG(Bg + k0 + 128, ldb, 16384);
    BARv(); LGK0(); QUAD(1,0); BARv();
    // ph4
    if (!last) STG(Bg + (size_t)128 * ldb + k0 + 128, ldb, 24576);
    BARv(); LGK0(); QUAD(1,1);
    if (last) { VMC0(); } else { VMC4(); }   // tile t1 fully landed
    BARv();
    // ---- tile t1 (buf1) ----
    // ph5
    RDA(0,0,32768); RDA(1,0,32768); RDA(2,0,32768); RDA(3,0,32768);
    RDB(0,32768); RDB(1,32768);
    if (!last) STG(Ag + k0 + 128, lda, 0);
    BARv(); LGK0(); QUAD(0,0); BARv();
    // ph6
    RDB(2,32768); RDB(3,32768);
    if (!last) STG(Ag + (size_t)128 * lda + k0 + 128, lda, 8192);
    BARv(); LGK0(); QUAD(0,1); BARv();
    // ph7
    RDA(0,1,32768); RDA(1,1,32768); RDA(2,1,32768); RDA(3,1,32768);
    if (!last) STG(Bg + k0 + 192, ldb, 32768 + 16384);
    BARv(); LGK0(); QUAD(1,0); BARv();
    // ph8
    if (!last) STG(Bg + (size_t)128 * ldb + k0 + 192, ldb, 32768 + 24576);
    BARv(); LGK0(); QUAD(1,1);
    if (!last) VMC4();                        // tile t0+2 fully landed
    BARv();
  }
#undef STG
#undef RDA
#undef RDB
#undef QUAD
}

// GEMM1: h[bk] = gelu(x[b] @ w_fc[e]) * w[bk]   -> bf16 [T][H]
__global__ __launch_bounds__(512, 2) void k_gemm1(
    const unsigned short* __restrict__ Xb, const unsigned short* __restrict__ Wfct,
    const int* __restrict__ sel, const float* __restrict__ wv,
    unsigned short* __restrict__ Hout) {
  __shared__ unsigned short LDS[65536];  // 128 KiB
  int flat = blockIdx.x + 16 * (blockIdx.y + 4 * blockIdx.z);   // nwg=1024
  int swz = (flat & 7) * 128 + (flat >> 3);                     // XCD-bijective
  const int bx = swz & 15, by = (swz >> 4) & 3, bk = swz >> 6;
  const int e = sel[bk];
  const float wgt = wv[bk];
  const int row0 = by * 256, col0 = bx * 256;
  v4f acc[8][4];
#pragma unroll
  for (int i = 0; i < 8; ++i)
#pragma unroll
    for (int j = 0; j < 4; ++j) acc[i][j] = (v4f){0.f, 0.f, 0.f, 0.f};

  gemm256(Xb + (size_t)(bk >> 1) * T_ * C_ + (size_t)row0 * C_,
          Wfct + (size_t)e * H_ * C_ + (size_t)col0 * C_,
          C_, C_, C_, LDS, acc);

  const int tid = threadIdx.x;
  const int lane = tid & 63;
  const int w = tid >> 6, wm = w >> 2, wn = w & 3;
  const int rr = lane & 15, q = lane >> 4;
  unsigned short* Co = Hout + (size_t)bk * T_ * H_;
  // padded LDS bounce: [128][272] shorts (row stride 544 B, 16B-aligned)
#pragma unroll
  for (int h = 0; h < 2; ++h) {
    if (wm == h) {
#pragma unroll
      for (int i = 0; i < 8; ++i)
#pragma unroll
        for (int j = 0; j < 4; ++j)
#pragma unroll
          for (int p = 0; p < 4; ++p) {
            int lr = i * 16 + q * 4 + p;
            int lc = wn * 64 + j * 16 + rr;
            float u = acc[i][j][p];
            float y = 0.7978845608028654f * (u + 0.044715f * u * u * u);
            float t = 1.0f - 2.0f / (__expf(2.0f * y) + 1.0f);
            LDS[lr * 272 + lc] = f2bf(0.5f * u * (1.0f + t) * wgt);
          }
    }
    __syncthreads();
#pragma unroll
    for (int m = 0; m < 8; ++m) {
      int idx = m * 512 + tid;
      int row = idx >> 5, cc = idx & 31;
      *(v8s*)&Co[(size_t)(row0 + h * 128 + row) * H_ + col0 + cc * 8] =
          *(const v8s*)&LDS[row * 272 + cc * 8];
    }
    __syncthreads();
  }
}

// GEMM2 (split over the two selected experts): one (b,k) per z-slice.
__global__ __launch_bounds__(512, 2) void k_gemm2(
    const unsigned short* __restrict__ Hin, const unsigned short* __restrict__ Wpt,
    const int* __restrict__ sel, float* __restrict__ P0, float* __restrict__ P1) {
  __shared__ unsigned short LDS[65536];
  int flat = blockIdx.x + 4 * (blockIdx.y + 4 * blockIdx.z);    // nwg=256
  int swz = (flat & 7) * 32 + (flat >> 3);
  const int bx = swz & 3, by = (swz >> 2) & 3, bk = swz >> 4;
  const int b = bk >> 1, k = bk & 1;
  const int e = sel[bk];
  const int row0 = by * 256, col0 = bx * 256;
  v4f acc[8][4];
#pragma unroll
  for (int i = 0; i < 8; ++i)
#pragma unroll
    for (int j = 0; j < 4; ++j) acc[i][j] = (v4f){0.f, 0.f, 0.f, 0.f};

  gemm256(Hin + (size_t)bk * T_ * H_ + (size_t)row0 * H_,
          Wpt + (size_t)e * C_ * H_ + (size_t)col0 * H_,
          H_, H_, H_, LDS, acc);

  const int tid = threadIdx.x;
  const int lane = tid & 63;
  const int w = tid >> 6, wm = w >> 2, wn = w & 3;
  const int rr = lane & 15, q = lane >> 4;
  float* Co = (k == 0 ? P0 : P1) + (size_t)b * T_ * C_;
#pragma unroll
  for (int i = 0; i < 8; ++i) {
    int gr = row0 + wm * 128 + i * 16 + q * 4;
#pragma unroll
    for (int j = 0; j < 4; ++j) {
      int gc = col0 + wn * 64 + j * 16 + rr;
#pragma unroll
      for (int p = 0; p < 4; ++p)
        Co[(size_t)(gr + p) * C_ + gc] = acc[i][j][p];
    }
  }
}

// out += P1
__global__ void k_add(float* __restrict__ out, const float* __restrict__ p1) {
  size_t i = ((size_t)blockIdx.x * 256 + threadIdx.x) * 4;
  v4f a = *(const v4f*)(out + i);
  v4f b = *(const v4f*)(p1 + i);
  a += b;
  *(v4f*)(out + i) = a;
}

// ---------------- launch ----------------

extern "C" void kernel_launch(void* const* d_in, const int* in_sizes, int n_in,
                              void* d_out, int out_size, void* d_ws, size_t ws_size,
                              hipStream_t stream) {
  const float* x   = (const float*)d_in[0];
  const float* rw  = (const float*)d_in[1];
  const float* wfc = (const float*)d_in[2];
  const float* wpj = (const float*)d_in[3];
  float* out = (float*)d_out;
  char* ws = (char*)d_ws;

  float*          part = (float*)(ws + 0);                        // 1 MB
  int*            sel  = (int*)(ws + 1048576);
  float*          wv   = (float*)(ws + 1048576 + 64);
  unsigned short* xb   = (unsigned short*)(ws + 2097152);         // 16 MB
  unsigned short* wfct = (unsigned short*)(ws + 2097152 + 16777216);            // 64 MB
  unsigned short* wpjt = (unsigned short*)(ws + 2097152 + 16777216 + 67108864); // 64 MB
  unsigned short* h    = (unsigned short*)(ws + 2097152 + 16777216 + 2*67108864ll); // 128 MB
  float*          p1   = (float*)(ws + 2097152);  // aliases dead xb+wfct after gemm1

  k_meanpart<<<dim3(B_ * 32), dim3(256), 0, stream>>>(x, part, xb);
  k_router<<<dim3(1), dim3(256), 0, stream>>>(part, rw, sel, wv,
                                              out + (size_t)B_ * T_ * C_);
  k_transpose<<<dim3(H_ / 64, C_ / 64, E_), dim3(256), 0, stream>>>(wfc, wfct, C_, H_);
  k_transpose<<<dim3(C_ / 64, H_ / 64, E_), dim3(256), 0, stream>>>(wpj, wpjt, H_, C_);

  k_gemm1<<<dim3(H_ / 256, T_ / 256, B_ * 2), dim3(512), 0, stream>>>(xb, wfct, sel, wv, h);
  k_gemm2<<<dim3(C_ / 256, T_ / 256, B_ * 2), dim3(512), 0, stream>>>(h, wpjt, sel, out, p1);
  k_add<<<dim3(B_ * T_ * C_ / 4 / 256), dim3(256), 0, stream>>>(out, p1);
}